// Round 1
// baseline (528.407 us; speedup 1.0000x reference)
//
#include <hip/hip_runtime.h>
#include <hip/hip_bf16.h>
#include <math.h>

// Problem constants (from reference)
constexpr int NN  = 10000;   // nodes
constexpr int NE  = 160000;  // edges (before self loops)
constexpr int GG  = 16;      // graphs
constexpr int HH  = 4;       // heads
constexpr int FF  = 128;     // per-head channels
constexpr int HF  = 512;     // H*F

// ---------------------------------------------------------------------------
// CSR build: group edges by dst. Self loops handled implicitly in aggregate.
// ---------------------------------------------------------------------------
__global__ void count_edges(const int* __restrict__ ei, int* __restrict__ counts) {
    int e = blockIdx.x * 256 + threadIdx.x;
    if (e < NE) atomicAdd(&counts[ei[NE + e]], 1);
}

__global__ void scan_offsets(const int* __restrict__ counts, int* __restrict__ offsets,
                             int* __restrict__ cursor) {
    __shared__ int s[256];
    __shared__ int total;
    if (threadIdx.x == 0) total = 0;
    __syncthreads();
    for (int base = 0; base < NN; base += 256) {
        int i = base + threadIdx.x;
        int v = (i < NN) ? counts[i] : 0;
        s[threadIdx.x] = v;
        __syncthreads();
        // Hillis-Steele inclusive scan
        for (int st = 1; st < 256; st <<= 1) {
            int t = (threadIdx.x >= st) ? s[threadIdx.x - st] : 0;
            __syncthreads();
            s[threadIdx.x] += t;
            __syncthreads();
        }
        int excl = s[threadIdx.x] - v + total;
        if (i < NN) { offsets[i] = excl; cursor[i] = excl; }
        __syncthreads();
        if (threadIdx.x == 0) total += s[255];
        __syncthreads();
    }
    if (threadIdx.x == 0) offsets[NN] = total;
}

__global__ void scatter_edges(const int* __restrict__ ei, int* __restrict__ cursor,
                              int* __restrict__ adj) {
    int e = blockIdx.x * 256 + threadIdx.x;
    if (e < NE) {
        int dst = ei[NE + e];
        int pos = atomicAdd(&cursor[dst], 1);
        adj[pos] = ei[e];  // store src
    }
}

// ---------------------------------------------------------------------------
// fp32 tiled GEMM: C[M,Nc] = A[M,K] @ B[K,Nc].  BM=BN=64, BK=16, 256 thr, 4x4.
// ---------------------------------------------------------------------------
__global__ __launch_bounds__(256) void gemm_fp32(const float* __restrict__ A,
                                                 const float* __restrict__ B,
                                                 float* __restrict__ C,
                                                 int M, int K, int Nc) {
    __shared__ float As[16][68];  // [k][m], padded for float4-aligned rows
    __shared__ float Bs[16][68];  // [k][n]
    int tid = threadIdx.x;
    int bm = blockIdx.x * 64, bn = blockIdx.y * 64;
    int tx = tid & 15, ty = tid >> 4;
    float acc[4][4] = {};
    for (int k0 = 0; k0 < K; k0 += 16) {
#pragma unroll
        for (int r = 0; r < 4; r++) {
            int idx = tid + r * 256;
            int m = idx >> 4, kk = idx & 15;
            int row = bm + m;
            As[kk][m] = (row < M) ? A[(size_t)row * K + k0 + kk] : 0.f;
        }
#pragma unroll
        for (int r = 0; r < 4; r++) {
            int idx = tid + r * 256;
            int kk = idx >> 6, nn = idx & 63;
            Bs[kk][nn] = B[(size_t)(k0 + kk) * Nc + bn + nn];
        }
        __syncthreads();
#pragma unroll
        for (int kk = 0; kk < 16; kk++) {
            float4 a4 = *(const float4*)&As[kk][ty * 4];
            float4 b4 = *(const float4*)&Bs[kk][tx * 4];
            float av[4] = {a4.x, a4.y, a4.z, a4.w};
            float bv[4] = {b4.x, b4.y, b4.z, b4.w};
#pragma unroll
            for (int i = 0; i < 4; i++)
#pragma unroll
                for (int j = 0; j < 4; j++) acc[i][j] += av[i] * bv[j];
        }
        __syncthreads();
    }
#pragma unroll
    for (int i = 0; i < 4; i++) {
        int row = bm + ty * 4 + i;
        if (row < M) {
            float4 v = {acc[i][0], acc[i][1], acc[i][2], acc[i][3]};
            *(float4*)&C[(size_t)row * Nc + bn + tx * 4] = v;
        }
    }
}

// ---------------------------------------------------------------------------
// Per-node attention coefficients: es[n,h] = h[n,h,:].a_s[h,:], ed likewise.
// One wave per node (4 nodes per 256-thread block).
// ---------------------------------------------------------------------------
__global__ __launch_bounds__(256) void attn_coef(const float* __restrict__ h,
                                                 const float* __restrict__ a_s,
                                                 const float* __restrict__ a_d,
                                                 float* __restrict__ es,
                                                 float* __restrict__ ed) {
    int wave = threadIdx.x >> 6, lane = threadIdx.x & 63;
    int n = blockIdx.x * 4 + wave;
    if (n >= NN) return;
    const float* hr = h + (size_t)n * HF;
#pragma unroll
    for (int hh = 0; hh < HH; hh++) {
        float v1 = hr[hh * FF + lane];
        float v2 = hr[hh * FF + 64 + lane];
        float ps = v1 * a_s[hh * FF + lane] + v2 * a_s[hh * FF + 64 + lane];
        float pd = v1 * a_d[hh * FF + lane] + v2 * a_d[hh * FF + 64 + lane];
#pragma unroll
        for (int off = 32; off; off >>= 1) {
            ps += __shfl_down(ps, off);
            pd += __shfl_down(pd, off);
        }
        if (lane == 0) { es[n * HH + hh] = ps; ed[n * HH + hh] = pd; }
    }
}

// ---------------------------------------------------------------------------
// Per-node segment softmax + aggregation.  Block = 512 threads = one node.
// MODE 0: concat heads -> out[N,512], +bias, ReLU.
// MODE 1: mean over heads -> out[N,128], +bias, no ReLU.
// Self loop (src = n) appended implicitly as the last edge.
// ---------------------------------------------------------------------------
template <int MODE>
__global__ __launch_bounds__(512) void gat_aggregate(const float* __restrict__ h,
                                                     const float* __restrict__ es,
                                                     const float* __restrict__ ed,
                                                     const int* __restrict__ offsets,
                                                     const int* __restrict__ adj,
                                                     const float* __restrict__ bias,
                                                     float* __restrict__ out) {
    constexpr int CH = 128;
    int n = blockIdx.x;
    int tid = threadIdx.x;
    int hh = tid >> 7;  // head of this thread
    __shared__ int s_src[CH];
    __shared__ float s_e[CH][4];
    __shared__ float s_m[4], s_d[4];
    __shared__ float s_tmp[512];

    int row0 = offsets[n];
    int deg = offsets[n + 1] - row0;
    int tot = deg + 1;  // + self loop

    // ---- pass 1: per-head max ----
    float mloc = -INFINITY;
    for (int cb = 0; cb < tot; cb += CH) {
        int cn = min(CH, tot - cb);
        if (tid < cn) {
            int idx = cb + tid;
            s_src[tid] = (idx < deg) ? adj[row0 + idx] : n;
        }
        __syncthreads();
        if (tid < cn * 4) {
            int i = tid >> 2, hq = tid & 3;
            float e = es[s_src[i] * 4 + hq] + ed[n * 4 + hq];
            e = (e >= 0.f) ? e : 0.2f * e;  // leaky_relu
            s_e[i][hq] = e;
        }
        __syncthreads();
        if (tid < 4) {
            for (int i = 0; i < cn; i++) mloc = fmaxf(mloc, s_e[i][tid]);
        }
        __syncthreads();
    }
    if (tid < 4) s_m[tid] = mloc;
    __syncthreads();

    // ---- pass 2: per-head sum of exp(e - m) ----
    float dloc = 0.f;
    for (int cb = 0; cb < tot; cb += CH) {
        int cn = min(CH, tot - cb);
        if (tid < cn) {
            int idx = cb + tid;
            s_src[tid] = (idx < deg) ? adj[row0 + idx] : n;
        }
        __syncthreads();
        if (tid < cn * 4) {
            int i = tid >> 2, hq = tid & 3;
            float e = es[s_src[i] * 4 + hq] + ed[n * 4 + hq];
            e = (e >= 0.f) ? e : 0.2f * e;
            s_e[i][hq] = __expf(e - s_m[hq]);
        }
        __syncthreads();
        if (tid < 4) {
            for (int i = 0; i < cn; i++) dloc += s_e[i][tid];
        }
        __syncthreads();
    }
    if (tid < 4) s_d[tid] = dloc;
    __syncthreads();

    // ---- pass 3: alpha-weighted gather-accumulate ----
    float acc = 0.f;
    for (int cb = 0; cb < tot; cb += CH) {
        int cn = min(CH, tot - cb);
        if (tid < cn) {
            int idx = cb + tid;
            s_src[tid] = (idx < deg) ? adj[row0 + idx] : n;
        }
        __syncthreads();
        if (tid < cn * 4) {
            int i = tid >> 2, hq = tid & 3;
            float e = es[s_src[i] * 4 + hq] + ed[n * 4 + hq];
            e = (e >= 0.f) ? e : 0.2f * e;
            s_e[i][hq] = __expf(e - s_m[hq]) / s_d[hq];
        }
        __syncthreads();
        for (int i = 0; i < cn; i++) {
            int s = s_src[i];
            acc += s_e[i][hh] * h[(size_t)s * HF + tid];
        }
        __syncthreads();
    }

    if (MODE == 0) {
        out[(size_t)n * HF + tid] = fmaxf(acc + bias[tid], 0.f);
    } else {
        s_tmp[tid] = acc;
        __syncthreads();
        if (tid < FF) {
            float v = 0.25f * (s_tmp[tid] + s_tmp[FF + tid] + s_tmp[2 * FF + tid] +
                               s_tmp[3 * FF + tid]) + bias[tid];
            out[(size_t)n * FF + tid] = v;
        }
    }
}

// ---------------------------------------------------------------------------
// Global mean pool (sum + count), low-contention: block handles 64 sorted nodes.
// ---------------------------------------------------------------------------
__global__ __launch_bounds__(128) void pool_kernel(const float* __restrict__ h2,
                                                   const int* __restrict__ batch,
                                                   float* __restrict__ sums,
                                                   float* __restrict__ cnts) {
    int f = threadIdx.x;  // 128 threads = feature
    int start = blockIdx.x * 64;
    float acc = 0.f;
    int curg = -1;
    for (int i = 0; i < 64; i++) {
        int node = start + i;
        if (node >= NN) break;
        int g = batch[node];
        if (g != curg) {
            if (curg >= 0) atomicAdd(&sums[curg * FF + f], acc);
            acc = 0.f;
            curg = g;
        }
        acc += h2[(size_t)node * FF + f];
    }
    if (curg >= 0) atomicAdd(&sums[curg * FF + f], acc);
    if (f == 0) {
        int cacc = 0, cg = -1;
        for (int i = 0; i < 64; i++) {
            int node = start + i;
            if (node >= NN) break;
            int g = batch[node];
            if (g != cg) {
                if (cg >= 0) atomicAdd(&cnts[cg], (float)cacc);
                cacc = 0;
                cg = g;
            }
            cacc++;
        }
        if (cg >= 0) atomicAdd(&cnts[cg], (float)cacc);
    }
}

// ---------------------------------------------------------------------------
// Final MLP: g = sums/cnt; z = relu(g@Wr1+br1); out = z@Wr2+br2.  Block/graph.
// ---------------------------------------------------------------------------
__global__ __launch_bounds__(256) void mlp_kernel(const float* __restrict__ sums,
                                                  const float* __restrict__ cnts,
                                                  const float* __restrict__ Wr1,
                                                  const float* __restrict__ br1,
                                                  const float* __restrict__ Wr2,
                                                  const float* __restrict__ br2,
                                                  float* __restrict__ out) {
    int g = blockIdx.x, t = threadIdx.x;
    __shared__ float gv[128];
    __shared__ float z[128];
    float c = fmaxf(cnts[g], 1.0f);
    if (t < 128) gv[t] = sums[g * FF + t] / c;
    __syncthreads();
    if (t < 128) {
        float a = br1[t];
        for (int k = 0; k < 128; k++) a += gv[k] * Wr1[k * 128 + t];
        z[t] = fmaxf(a, 0.f);
    }
    __syncthreads();
    {
        float a = br2[t];
        for (int k = 0; k < 128; k++) a += z[k] * Wr2[k * 256 + t];
        out[g * 256 + t] = a;
    }
}

// ---------------------------------------------------------------------------
extern "C" void kernel_launch(void* const* d_in, const int* in_sizes, int n_in,
                              void* d_out, int out_size, void* d_ws, size_t ws_size,
                              hipStream_t stream) {
    const float* x    = (const float*)d_in[0];
    const int*   ei   = (const int*)d_in[1];
    const int*   batch= (const int*)d_in[2];
    const float* W0   = (const float*)d_in[3];
    const float* as0  = (const float*)d_in[4];
    const float* ad0  = (const float*)d_in[5];
    const float* b0   = (const float*)d_in[6];
    const float* W1   = (const float*)d_in[7];
    const float* as1  = (const float*)d_in[8];
    const float* ad1  = (const float*)d_in[9];
    const float* b1   = (const float*)d_in[10];
    const float* W2   = (const float*)d_in[11];
    const float* as2  = (const float*)d_in[12];
    const float* ad2  = (const float*)d_in[13];
    const float* b2   = (const float*)d_in[14];
    const float* Wr1  = (const float*)d_in[15];
    const float* br1  = (const float*)d_in[16];
    const float* Wr2  = (const float*)d_in[17];
    const float* br2  = (const float*)d_in[18];
    float* out = (float*)d_out;

    char* p = (char*)d_ws;
    auto alloc = [&](size_t bytes) {
        char* r = p;
        p += (bytes + 255) / 256 * 256;
        return r;
    };
    float* hA      = (float*)alloc((size_t)NN * HF * 4);
    float* hB      = (float*)alloc((size_t)NN * HF * 4);
    float* h2      = (float*)alloc((size_t)NN * FF * 4);
    float* es      = (float*)alloc((size_t)NN * HH * 4);
    float* ed      = (float*)alloc((size_t)NN * HH * 4);
    int*   counts  = (int*)alloc((size_t)NN * 4);
    int*   offsets = (int*)alloc((size_t)(NN + 1) * 4);
    int*   cursor  = (int*)alloc((size_t)NN * 4);
    int*   adj     = (int*)alloc((size_t)NE * 4);
    float* sums    = (float*)alloc((size_t)GG * FF * 4);
    float* cnts    = (float*)alloc((size_t)GG * 4);

    // ---- CSR build (reused by all 3 layers) ----
    hipMemsetAsync(counts, 0, NN * 4, stream);
    count_edges<<<(NE + 255) / 256, 256, 0, stream>>>(ei, counts);
    scan_offsets<<<1, 256, 0, stream>>>(counts, offsets, cursor);
    scatter_edges<<<(NE + 255) / 256, 256, 0, stream>>>(ei, cursor, adj);

    dim3 ggemm((NN + 63) / 64, HF / 64);

    // ---- layer 0 ----
    gemm_fp32<<<ggemm, 256, 0, stream>>>(x, W0, hA, NN, 64, HF);
    attn_coef<<<(NN + 3) / 4, 256, 0, stream>>>(hA, as0, ad0, es, ed);
    gat_aggregate<0><<<NN, 512, 0, stream>>>(hA, es, ed, offsets, adj, b0, hB);

    // ---- layer 1 ----
    gemm_fp32<<<ggemm, 256, 0, stream>>>(hB, W1, hA, NN, HF, HF);
    attn_coef<<<(NN + 3) / 4, 256, 0, stream>>>(hA, as1, ad1, es, ed);
    gat_aggregate<0><<<NN, 512, 0, stream>>>(hA, es, ed, offsets, adj, b1, hB);

    // ---- layer 2 ----
    gemm_fp32<<<ggemm, 256, 0, stream>>>(hB, W2, hA, NN, HF, HF);
    attn_coef<<<(NN + 3) / 4, 256, 0, stream>>>(hA, as2, ad2, es, ed);
    gat_aggregate<1><<<NN, 512, 0, stream>>>(hA, es, ed, offsets, adj, b2, h2);

    // ---- pool + MLP ----
    hipMemsetAsync(sums, 0, (GG * FF + GG) * 4, stream);  // sums and cnts contiguous
    pool_kernel<<<(NN + 63) / 64, 128, 0, stream>>>(h2, batch, sums, cnts);
    mlp_kernel<<<GG, 256, 0, stream>>>(sums, cnts, Wr1, br1, Wr2, br2, out);
}

// Round 2
// 311.951 us; speedup vs baseline: 1.6939x; 1.6939x over previous
//
#include <hip/hip_runtime.h>
#include <hip/hip_bf16.h>
#include <math.h>

// Problem constants (from reference)
constexpr int NN  = 10000;   // nodes
constexpr int NE  = 160000;  // edges (before self loops)
constexpr int GG  = 16;      // graphs
constexpr int HH  = 4;       // heads
constexpr int FF  = 128;     // per-head channels
constexpr int HF  = 512;     // H*F

typedef __attribute__((ext_vector_type(8))) short bf16x8;
typedef __attribute__((ext_vector_type(4))) float f32x4;

__device__ inline short f2bf(float v) {
    __hip_bfloat16 h = __float2bfloat16(v);
    return *reinterpret_cast<short*>(&h);
}
__device__ inline float bf2f(short s) {
    __hip_bfloat16 h = *reinterpret_cast<__hip_bfloat16*>(&s);
    return __bfloat162float(h);
}

// ---------------------------------------------------------------------------
// CSR build: group edges by dst. Self loops handled implicitly in aggregate.
// ---------------------------------------------------------------------------
__global__ void count_edges(const int* __restrict__ ei, int* __restrict__ counts) {
    int e = blockIdx.x * 256 + threadIdx.x;
    if (e < NE) atomicAdd(&counts[ei[NE + e]], 1);
}

__global__ __launch_bounds__(1024) void scan_offsets(const int* __restrict__ counts,
                                                     int* __restrict__ offsets,
                                                     int* __restrict__ cursor) {
    __shared__ int wsum[16];
    __shared__ int carry;
    int tid = threadIdx.x, lane = tid & 63, wv = tid >> 6;
    if (tid == 0) carry = 0;
    __syncthreads();
    for (int base = 0; base < NN; base += 1024) {
        int i = base + tid;
        int v = (i < NN) ? counts[i] : 0;
        int x = v;
#pragma unroll
        for (int st = 1; st < 64; st <<= 1) {
            int t = __shfl_up(x, st);
            if (lane >= st) x += t;
        }
        if (lane == 63) wsum[wv] = x;
        __syncthreads();
        if (tid == 0) {
            int s = carry;
            for (int k2 = 0; k2 < 16; k2++) { int t = wsum[k2]; wsum[k2] = s; s += t; }
            carry = s;
        }
        __syncthreads();
        int excl = wsum[wv] + x - v;
        if (i < NN) { offsets[i] = excl; cursor[i] = excl; }
        __syncthreads();
    }
    if (tid == 0) offsets[NN] = carry;
}

__global__ void scatter_edges(const int* __restrict__ ei, int* __restrict__ cursor,
                              int* __restrict__ adj) {
    int e = blockIdx.x * 256 + threadIdx.x;
    if (e < NE) {
        int dst = ei[NE + e];
        int pos = atomicAdd(&cursor[dst], 1);
        adj[pos] = ei[e];  // store src
    }
}

// ---------------------------------------------------------------------------
// Conversions: x -> bf16; W [K,HF] fp32 -> W^T hi/lo bf16 [HF,K]
// ---------------------------------------------------------------------------
__global__ void convert_x(const float* __restrict__ x, short* __restrict__ xb, int total) {
    int i = blockIdx.x * 256 + threadIdx.x;
    if (i < total) xb[i] = f2bf(x[i]);
}

__global__ __launch_bounds__(256) void transpose_hilo(const float* __restrict__ W,
                                                      short* __restrict__ Thi,
                                                      short* __restrict__ Tlo,
                                                      int K, int Nc) {
    __shared__ float tile[32][33];
    int bn = blockIdx.x * 32, bk = blockIdx.y * 32;
    int tx = threadIdx.x & 31, ty = threadIdx.x >> 5;  // ty 0..7
    for (int r = ty; r < 32; r += 8) {
        int k = bk + r, n = bn + tx;
        tile[r][tx] = (k < K && n < Nc) ? W[(size_t)k * Nc + n] : 0.f;
    }
    __syncthreads();
    for (int r = ty; r < 32; r += 8) {
        int n = bn + r, k = bk + tx;
        if (n < Nc && k < K) {
            float v = tile[tx][r];
            short hi = f2bf(v);
            short lo = f2bf(v - bf2f(hi));
            Thi[(size_t)n * K + k] = hi;
            Tlo[(size_t)n * K + k] = lo;
        }
    }
}

// ---------------------------------------------------------------------------
// bf16 MFMA GEMM: C[M,Nc]fp32 = A[M,K]bf16 @ (Bhi+Blo)[Nc,K]bf16^T
// BM=BN=128, BK=32, 256 threads = 4 waves (2x2 of 64x64), 4x4 16x16 frags.
// B given transposed [n][k] so both frags are contiguous ds_read_b128.
// ---------------------------------------------------------------------------
__global__ __launch_bounds__(256) void gemm_bf16(const short* __restrict__ A,
                                                 const short* __restrict__ Bhi,
                                                 const short* __restrict__ Blo,
                                                 float* __restrict__ C,
                                                 int M, int K, int Nc) {
    constexpr int BM = 128, BK = 32, LDT = BK + 8;  // pad 16B
    __shared__ short As[BM][LDT];
    __shared__ short Bh[BM][LDT];
    __shared__ short Bl[BM][LDT];
    int tid = threadIdx.x;
    int wave = tid >> 6, lane = tid & 63;
    int wr = wave >> 1, wc = wave & 1;
    int fr = lane & 15, fq = lane >> 4;
    int bm = blockIdx.x * BM, bn = blockIdx.y * BM;
    int srow = tid >> 2;          // 0..63
    int scol = (tid & 3) * 8;     // 0,8,16,24
    f32x4 acc[4][4] = {};
    for (int k0 = 0; k0 < K; k0 += BK) {
#pragma unroll
        for (int p = 0; p < 2; p++) {
            int r = srow + 64 * p;
            int row = bm + r;
            bf16x8 va = {};
            if (row < M) va = *(const bf16x8*)&A[(size_t)row * K + k0 + scol];
            *(bf16x8*)&As[r][scol] = va;
            bf16x8 vh = *(const bf16x8*)&Bhi[(size_t)(bn + r) * K + k0 + scol];
            *(bf16x8*)&Bh[r][scol] = vh;
            bf16x8 vl = *(const bf16x8*)&Blo[(size_t)(bn + r) * K + k0 + scol];
            *(bf16x8*)&Bl[r][scol] = vl;
        }
        __syncthreads();
        bf16x8 af[4], bh[4], bl[4];
#pragma unroll
        for (int m = 0; m < 4; m++)
            af[m] = *(const bf16x8*)&As[wr * 64 + m * 16 + fr][fq * 8];
#pragma unroll
        for (int n = 0; n < 4; n++) {
            bh[n] = *(const bf16x8*)&Bh[wc * 64 + n * 16 + fr][fq * 8];
            bl[n] = *(const bf16x8*)&Bl[wc * 64 + n * 16 + fr][fq * 8];
        }
#pragma unroll
        for (int m = 0; m < 4; m++)
#pragma unroll
            for (int n = 0; n < 4; n++) {
                acc[m][n] = __builtin_amdgcn_mfma_f32_16x16x32_bf16(af[m], bh[n], acc[m][n], 0, 0, 0);
                acc[m][n] = __builtin_amdgcn_mfma_f32_16x16x32_bf16(af[m], bl[n], acc[m][n], 0, 0, 0);
            }
        __syncthreads();
    }
    // C/D layout: col = lane&15, row = (lane>>4)*4 + j   [verified m89]
#pragma unroll
    for (int m = 0; m < 4; m++) {
#pragma unroll
        for (int j = 0; j < 4; j++) {
            int row = bm + wr * 64 + m * 16 + fq * 4 + j;
            if (row < M) {
#pragma unroll
                for (int n = 0; n < 4; n++) {
                    int col = bn + wc * 64 + n * 16 + fr;
                    C[(size_t)row * Nc + col] = acc[m][n][j];
                }
            }
        }
    }
}

// ---------------------------------------------------------------------------
// Per-node attention coefficients: es[n,h] = h[n,h,:].a_s[h,:], ed likewise.
// One wave per node (4 nodes per 256-thread block), float2 loads.
// ---------------------------------------------------------------------------
__global__ __launch_bounds__(256) void attn_coef(const float* __restrict__ h,
                                                 const float* __restrict__ a_s,
                                                 const float* __restrict__ a_d,
                                                 float* __restrict__ es,
                                                 float* __restrict__ ed) {
    int wavei = threadIdx.x >> 6, lane = threadIdx.x & 63;
    int n = blockIdx.x * 4 + wavei;
    if (n >= NN) return;
    const float* hr = h + (size_t)n * HF;
#pragma unroll
    for (int hh = 0; hh < HH; hh++) {
        float2 hv  = *(const float2*)&hr[hh * FF + lane * 2];
        float2 asv = *(const float2*)&a_s[hh * FF + lane * 2];
        float2 adv = *(const float2*)&a_d[hh * FF + lane * 2];
        float ps = hv.x * asv.x + hv.y * asv.y;
        float pd = hv.x * adv.x + hv.y * adv.y;
#pragma unroll
        for (int off = 32; off; off >>= 1) {
            ps += __shfl_down(ps, off);
            pd += __shfl_down(pd, off);
        }
        if (lane == 0) { es[n * HH + hh] = ps; ed[n * HH + hh] = pd; }
    }
}

// ---------------------------------------------------------------------------
// Segment softmax + aggregation. 256 threads = 4 waves = 1 node; wave = head.
// Softmax stats via wave shfl reductions; denominator folded at the end.
// MODE 0: concat + bias + ReLU -> bf16 [N,512] (feeds next GEMM)
// MODE 1: head-mean + bias     -> fp32 [N,128]
// ---------------------------------------------------------------------------
template <int MODE>
__global__ __launch_bounds__(256) void gat_aggregate(const float* __restrict__ h,
                                                     const float* __restrict__ es,
                                                     const float* __restrict__ ed,
                                                     const int* __restrict__ offsets,
                                                     const int* __restrict__ adj,
                                                     const float* __restrict__ bias,
                                                     float* __restrict__ outf,
                                                     short* __restrict__ outb) {
    constexpr int CAP = 1024;
    int n = blockIdx.x;
    int tid = threadIdx.x, w = tid >> 6, lane = tid & 63;
    __shared__ int s_src[CAP];
    __shared__ float s_wt[4][CAP];
    __shared__ float s_out[4][FF];
    int row0 = offsets[n];
    int deg = offsets[n + 1] - row0;
    int tot = min(deg + 1, CAP);  // + self loop
    for (int i = tid; i < tot; i += 256)
        s_src[i] = (i < deg) ? adj[row0 + i] : n;
    __syncthreads();
    float edn = ed[n * 4 + w];
    float m = -1e30f;
    for (int i = lane; i < tot; i += 64) {
        float e = es[s_src[i] * 4 + w] + edn;
        e = (e >= 0.f) ? e : 0.2f * e;  // leaky_relu
        s_wt[w][i] = e;
        m = fmaxf(m, e);
    }
#pragma unroll
    for (int off = 32; off; off >>= 1) m = fmaxf(m, __shfl_xor(m, off));
    float sum = 0.f;
    for (int i = lane; i < tot; i += 64) {
        float v = __expf(s_wt[w][i] - m);
        s_wt[w][i] = v;
        sum += v;
    }
#pragma unroll
    for (int off = 32; off; off >>= 1) sum += __shfl_xor(sum, off);
    float rd = 1.f / sum;
    __syncthreads();
    float ax = 0.f, ay = 0.f;
    const float* hcol = h + w * FF + lane * 2;
    for (int i = 0; i < tot; i++) {
        int s = s_src[i];
        float wt = s_wt[w][i];
        float2 hv = *(const float2*)&hcol[(size_t)s * HF];
        ax += wt * hv.x;
        ay += wt * hv.y;
    }
    ax *= rd;
    ay *= rd;
    int c = w * FF + lane * 2;
    if (MODE == 0) {
        short2 sv;
        sv.x = f2bf(fmaxf(ax + bias[c], 0.f));
        sv.y = f2bf(fmaxf(ay + bias[c + 1], 0.f));
        *(short2*)&outb[(size_t)n * HF + c] = sv;
    } else {
        s_out[w][lane * 2] = ax;
        s_out[w][lane * 2 + 1] = ay;
        __syncthreads();
        if (tid < FF) {
            float v = 0.25f * (s_out[0][tid] + s_out[1][tid] + s_out[2][tid] + s_out[3][tid]) +
                      bias[tid];
            outf[(size_t)n * FF + tid] = v;
        }
    }
}

// ---------------------------------------------------------------------------
// Global mean pool (sum + count), low-contention: block handles 64 sorted nodes.
// ---------------------------------------------------------------------------
__global__ __launch_bounds__(128) void pool_kernel(const float* __restrict__ h2,
                                                   const int* __restrict__ batch,
                                                   float* __restrict__ sums,
                                                   float* __restrict__ cnts) {
    int f = threadIdx.x;  // 128 threads = feature
    int start = blockIdx.x * 64;
    float acc = 0.f;
    int curg = -1;
    for (int i = 0; i < 64; i++) {
        int node = start + i;
        if (node >= NN) break;
        int g = batch[node];
        if (g != curg) {
            if (curg >= 0) atomicAdd(&sums[curg * FF + f], acc);
            acc = 0.f;
            curg = g;
        }
        acc += h2[(size_t)node * FF + f];
    }
    if (curg >= 0) atomicAdd(&sums[curg * FF + f], acc);
    if (f == 0) {
        int cacc = 0, cg = -1;
        for (int i = 0; i < 64; i++) {
            int node = start + i;
            if (node >= NN) break;
            int g = batch[node];
            if (g != cg) {
                if (cg >= 0) atomicAdd(&cnts[cg], (float)cacc);
                cacc = 0;
                cg = g;
            }
            cacc++;
        }
        if (cg >= 0) atomicAdd(&cnts[cg], (float)cacc);
    }
}

// ---------------------------------------------------------------------------
// Final MLP: g = sums/cnt; z = relu(g@Wr1+br1); out = z@Wr2+br2.  Block/graph.
// ---------------------------------------------------------------------------
__global__ __launch_bounds__(256) void mlp_kernel(const float* __restrict__ sums,
                                                  const float* __restrict__ cnts,
                                                  const float* __restrict__ Wr1,
                                                  const float* __restrict__ br1,
                                                  const float* __restrict__ Wr2,
                                                  const float* __restrict__ br2,
                                                  float* __restrict__ out) {
    int g = blockIdx.x, t = threadIdx.x;
    __shared__ float gv[128];
    __shared__ float z[128];
    float c = fmaxf(cnts[g], 1.0f);
    if (t < 128) gv[t] = sums[g * FF + t] / c;
    __syncthreads();
    if (t < 128) {
        float a = br1[t];
        for (int k = 0; k < 128; k++) a += gv[k] * Wr1[k * 128 + t];
        z[t] = fmaxf(a, 0.f);
    }
    __syncthreads();
    {
        float a = br2[t];
        for (int k = 0; k < 128; k++) a += z[k] * Wr2[k * 256 + t];
        out[g * 256 + t] = a;
    }
}

// ---------------------------------------------------------------------------
extern "C" void kernel_launch(void* const* d_in, const int* in_sizes, int n_in,
                              void* d_out, int out_size, void* d_ws, size_t ws_size,
                              hipStream_t stream) {
    const float* x    = (const float*)d_in[0];
    const int*   ei   = (const int*)d_in[1];
    const int*   batch= (const int*)d_in[2];
    const float* W0   = (const float*)d_in[3];
    const float* as0  = (const float*)d_in[4];
    const float* ad0  = (const float*)d_in[5];
    const float* b0   = (const float*)d_in[6];
    const float* W1   = (const float*)d_in[7];
    const float* as1  = (const float*)d_in[8];
    const float* ad1  = (const float*)d_in[9];
    const float* b1   = (const float*)d_in[10];
    const float* W2   = (const float*)d_in[11];
    const float* as2  = (const float*)d_in[12];
    const float* ad2  = (const float*)d_in[13];
    const float* b2   = (const float*)d_in[14];
    const float* Wr1  = (const float*)d_in[15];
    const float* br1  = (const float*)d_in[16];
    const float* Wr2  = (const float*)d_in[17];
    const float* br2  = (const float*)d_in[18];
    float* out = (float*)d_out;

    char* p = (char*)d_ws;
    auto alloc = [&](size_t bytes) {
        char* r = p;
        p += (bytes + 255) / 256 * 256;
        return r;
    };
    float* hA      = (float*)alloc((size_t)NN * HF * 4);   // GEMM out (fp32)
    short* hBb     = (short*)alloc((size_t)NN * HF * 2);   // aggregate out (bf16)
    float* h2      = (float*)alloc((size_t)NN * FF * 4);
    short* xb      = (short*)alloc((size_t)NN * 64 * 2);
    short* WThi    = (short*)alloc((size_t)HF * HF * 2);
    short* WTlo    = (short*)alloc((size_t)HF * HF * 2);
    float* es      = (float*)alloc((size_t)NN * HH * 4);
    float* ed      = (float*)alloc((size_t)NN * HH * 4);
    int*   counts  = (int*)alloc((size_t)NN * 4);
    int*   offsets = (int*)alloc((size_t)(NN + 1) * 4);
    int*   cursor  = (int*)alloc((size_t)NN * 4);
    int*   adj     = (int*)alloc((size_t)NE * 4);
    float* sums    = (float*)alloc((size_t)GG * FF * 4);
    float* cnts    = (float*)alloc((size_t)GG * 4);

    // ---- CSR build (reused by all 3 layers) ----
    hipMemsetAsync(counts, 0, NN * 4, stream);
    count_edges<<<(NE + 255) / 256, 256, 0, stream>>>(ei, counts);
    scan_offsets<<<1, 1024, 0, stream>>>(counts, offsets, cursor);
    scatter_edges<<<(NE + 255) / 256, 256, 0, stream>>>(ei, cursor, adj);

    // ---- input conversion ----
    convert_x<<<(NN * 64 + 255) / 256, 256, 0, stream>>>(x, xb, NN * 64);

    dim3 ggemm((NN + 127) / 128, HF / 128);

    // ---- layer 0 (K=64) ----
    transpose_hilo<<<dim3(HF / 32, 64 / 32), 256, 0, stream>>>(W0, WThi, WTlo, 64, HF);
    gemm_bf16<<<ggemm, 256, 0, stream>>>(xb, WThi, WTlo, hA, NN, 64, HF);
    attn_coef<<<(NN + 3) / 4, 256, 0, stream>>>(hA, as0, ad0, es, ed);
    gat_aggregate<0><<<NN, 256, 0, stream>>>(hA, es, ed, offsets, adj, b0, nullptr, hBb);

    // ---- layer 1 (K=512) ----
    transpose_hilo<<<dim3(HF / 32, HF / 32), 256, 0, stream>>>(W1, WThi, WTlo, HF, HF);
    gemm_bf16<<<ggemm, 256, 0, stream>>>(hBb, WThi, WTlo, hA, NN, HF, HF);
    attn_coef<<<(NN + 3) / 4, 256, 0, stream>>>(hA, as1, ad1, es, ed);
    gat_aggregate<0><<<NN, 256, 0, stream>>>(hA, es, ed, offsets, adj, b1, nullptr, hBb);

    // ---- layer 2 (K=512) ----
    transpose_hilo<<<dim3(HF / 32, HF / 32), 256, 0, stream>>>(W2, WThi, WTlo, HF, HF);
    gemm_bf16<<<ggemm, 256, 0, stream>>>(hBb, WThi, WTlo, hA, NN, HF, HF);
    attn_coef<<<(NN + 3) / 4, 256, 0, stream>>>(hA, as2, ad2, es, ed);
    gat_aggregate<1><<<NN, 256, 0, stream>>>(hA, es, ed, offsets, adj, b2, h2, nullptr);

    // ---- pool + MLP ----
    hipMemsetAsync(sums, 0, (GG * FF + GG) * 4, stream);  // sums and cnts contiguous
    pool_kernel<<<(NN + 63) / 64, 128, 0, stream>>>(h2, batch, sums, cnts);
    mlp_kernel<<<GG, 256, 0, stream>>>(sums, cnts, Wr1, br1, Wr2, br2, out);
}

// Round 3
// 221.751 us; speedup vs baseline: 2.3829x; 1.4068x over previous
//
#include <hip/hip_runtime.h>
#include <hip/hip_bf16.h>
#include <math.h>

// Problem constants (from reference)
constexpr int NN  = 10000;   // nodes
constexpr int NE  = 160000;  // edges (before self loops)
constexpr int GG  = 16;      // graphs
constexpr int HH  = 4;       // heads
constexpr int FF  = 128;     // per-head channels
constexpr int HF  = 512;     // H*F

typedef __attribute__((ext_vector_type(8))) short bf16x8;
typedef __attribute__((ext_vector_type(4))) float f32x4;

__device__ inline short f2bf(float v) {
    __hip_bfloat16 h = __float2bfloat16(v);
    return *reinterpret_cast<short*>(&h);
}
__device__ inline float bf2f(short s) {
    __hip_bfloat16 h = *reinterpret_cast<__hip_bfloat16*>(&s);
    return __bfloat162float(h);
}

// ---------------------------------------------------------------------------
// CSR build: group edges by dst. Self loops handled implicitly in aggregate.
// ---------------------------------------------------------------------------
__global__ void count_edges(const int* __restrict__ ei, int* __restrict__ counts) {
    int e = blockIdx.x * 256 + threadIdx.x;
    if (e < NE) atomicAdd(&counts[ei[NE + e]], 1);
}

__global__ __launch_bounds__(1024) void scan_offsets(const int* __restrict__ counts,
                                                     int* __restrict__ offsets,
                                                     int* __restrict__ cursor) {
    __shared__ int wsum[16];
    __shared__ int carry;
    int tid = threadIdx.x, lane = tid & 63, wv = tid >> 6;
    if (tid == 0) carry = 0;
    __syncthreads();
    for (int base = 0; base < NN; base += 1024) {
        int i = base + tid;
        int v = (i < NN) ? counts[i] : 0;
        int x = v;
#pragma unroll
        for (int st = 1; st < 64; st <<= 1) {
            int t = __shfl_up(x, st);
            if (lane >= st) x += t;
        }
        if (lane == 63) wsum[wv] = x;
        __syncthreads();
        if (tid == 0) {
            int s = carry;
            for (int k2 = 0; k2 < 16; k2++) { int t = wsum[k2]; wsum[k2] = s; s += t; }
            carry = s;
        }
        __syncthreads();
        int excl = wsum[wv] + x - v;
        if (i < NN) { offsets[i] = excl; cursor[i] = excl; }
        __syncthreads();
    }
    if (tid == 0) offsets[NN] = carry;
}

__global__ void scatter_edges(const int* __restrict__ ei, int* __restrict__ cursor,
                              int* __restrict__ adj) {
    int e = blockIdx.x * 256 + threadIdx.x;
    if (e < NE) {
        int dst = ei[NE + e];
        int pos = atomicAdd(&cursor[dst], 1);
        adj[pos] = ei[e];  // store src
    }
}

// ---------------------------------------------------------------------------
// Prep: z=0..2 -> W{z} [K,512] fp32 -> W^T hi/lo bf16 [512,K]; z=3 -> x->bf16
// ---------------------------------------------------------------------------
__global__ __launch_bounds__(256) void prep_kernel(const float* __restrict__ x,
                                                   short* __restrict__ xb,
                                                   const float* __restrict__ W0,
                                                   const float* __restrict__ W1,
                                                   const float* __restrict__ W2,
                                                   short* __restrict__ T0h, short* __restrict__ T0l,
                                                   short* __restrict__ T1h, short* __restrict__ T1l,
                                                   short* __restrict__ T2h, short* __restrict__ T2l) {
    int z = blockIdx.z;
    int tid = threadIdx.x;
    if (z == 3) {
        int bid = blockIdx.y * 16 + blockIdx.x;
        for (int i = bid * 256 + tid; i < NN * 64; i += 256 * 256)
            xb[i] = f2bf(x[i]);
        return;
    }
    const float* W = (z == 0) ? W0 : (z == 1) ? W1 : W2;
    short* Th = (z == 0) ? T0h : (z == 1) ? T1h : T2h;
    short* Tl = (z == 0) ? T0l : (z == 1) ? T1l : T2l;
    int K = (z == 0) ? 64 : HF;
    int bn = blockIdx.x * 32, bk = blockIdx.y * 32;
    if (bk >= K) return;  // block-uniform
    __shared__ float tile[32][33];
    int tx = tid & 31, ty = tid >> 5;  // ty 0..7
    for (int r = ty; r < 32; r += 8) {
        int k = bk + r, n = bn + tx;
        tile[r][tx] = W[(size_t)k * HF + n];
    }
    __syncthreads();
    for (int r = ty; r < 32; r += 8) {
        int n = bn + r, k = bk + tx;
        float v = tile[tx][r];
        short hi = f2bf(v);
        short lo = f2bf(v - bf2f(hi));
        Th[(size_t)n * K + k] = hi;
        Tl[(size_t)n * K + k] = lo;
    }
}

// ---------------------------------------------------------------------------
// bf16 MFMA GEMM + fused attention coefficients.
// C[M,512]bf16 = A[M,K]bf16 @ (Bhi+Blo)[512,K]^T, fp32 accum.
// BM=128, BN=128 = exactly one head (blockIdx.y), BK=32, 4 waves 2x2.
// Epilogue: es[row,head] = C_row . a_s[head], ed likewise (fp32 acc, exact),
// then C stored as bf16.
// ---------------------------------------------------------------------------
__global__ __launch_bounds__(256) void gemm_attn(const short* __restrict__ A,
                                                 const short* __restrict__ Bhi,
                                                 const short* __restrict__ Blo,
                                                 short* __restrict__ Cb,
                                                 float* __restrict__ es,
                                                 float* __restrict__ ed,
                                                 const float* __restrict__ a_s,
                                                 const float* __restrict__ a_d,
                                                 int M, int K) {
    constexpr int BM = 128, BK = 32, LDT = BK + 8;  // pad 16B
    __shared__ short As[BM][LDT];
    __shared__ short Bh[BM][LDT];
    __shared__ short Bl[BM][LDT];
    __shared__ float s_red[2][BM][2];
    int tid = threadIdx.x;
    int wave = tid >> 6, lane = tid & 63;
    int wr = wave >> 1, wc = wave & 1;
    int fr = lane & 15, fq = lane >> 4;
    int bm = blockIdx.x * BM;
    int head = blockIdx.y;
    int bn = head * FF;
    int srow = tid >> 2;          // 0..63
    int scol = (tid & 3) * 8;     // 0,8,16,24
    f32x4 acc[4][4] = {};
    for (int k0 = 0; k0 < K; k0 += BK) {
#pragma unroll
        for (int p = 0; p < 2; p++) {
            int r = srow + 64 * p;
            int row = bm + r;
            bf16x8 va = {};
            if (row < M) va = *(const bf16x8*)&A[(size_t)row * K + k0 + scol];
            *(bf16x8*)&As[r][scol] = va;
            *(bf16x8*)&Bh[r][scol] = *(const bf16x8*)&Bhi[(size_t)(bn + r) * K + k0 + scol];
            *(bf16x8*)&Bl[r][scol] = *(const bf16x8*)&Blo[(size_t)(bn + r) * K + k0 + scol];
        }
        __syncthreads();
        bf16x8 af[4], bh[4], bl[4];
#pragma unroll
        for (int m = 0; m < 4; m++)
            af[m] = *(const bf16x8*)&As[wr * 64 + m * 16 + fr][fq * 8];
#pragma unroll
        for (int n = 0; n < 4; n++) {
            bh[n] = *(const bf16x8*)&Bh[wc * 64 + n * 16 + fr][fq * 8];
            bl[n] = *(const bf16x8*)&Bl[wc * 64 + n * 16 + fr][fq * 8];
        }
#pragma unroll
        for (int m = 0; m < 4; m++)
#pragma unroll
            for (int n = 0; n < 4; n++) {
                acc[m][n] = __builtin_amdgcn_mfma_f32_16x16x32_bf16(af[m], bh[n], acc[m][n], 0, 0, 0);
                acc[m][n] = __builtin_amdgcn_mfma_f32_16x16x32_bf16(af[m], bl[n], acc[m][n], 0, 0, 0);
            }
        __syncthreads();
    }
    // ---- epilogue: fused attn dots + bf16 C store ----
    // C/D layout: col = lane&15, row = (lane>>4)*4 + j   [verified m89]
    float asv[4], adv[4];
#pragma unroll
    for (int n = 0; n < 4; n++) {
        int c = wc * 64 + n * 16 + fr;
        asv[n] = a_s[head * FF + c];
        adv[n] = a_d[head * FF + c];
    }
#pragma unroll
    for (int m = 0; m < 4; m++) {
#pragma unroll
        for (int j = 0; j < 4; j++) {
            float ps = 0.f, pd = 0.f;
#pragma unroll
            for (int n = 0; n < 4; n++) {
                float v = acc[m][n][j];
                ps += v * asv[n];
                pd += v * adv[n];
            }
#pragma unroll
            for (int o = 1; o < 16; o <<= 1) {
                ps += __shfl_xor(ps, o);
                pd += __shfl_xor(pd, o);
            }
            int rloc = wr * 64 + m * 16 + fq * 4 + j;
            if (fr == 0) { s_red[wc][rloc][0] = ps; s_red[wc][rloc][1] = pd; }
            int row = bm + rloc;
            if (row < M) {
#pragma unroll
                for (int n = 0; n < 4; n++)
                    Cb[(size_t)row * HF + bn + wc * 64 + n * 16 + fr] = f2bf(acc[m][n][j]);
            }
        }
    }
    __syncthreads();
    if (tid < BM) {
        int row = bm + tid;
        if (row < M) {
            es[row * 4 + head] = s_red[0][tid][0] + s_red[1][tid][0];
            ed[row * 4 + head] = s_red[0][tid][1] + s_red[1][tid][1];
        }
    }
}

// ---------------------------------------------------------------------------
// Segment softmax + aggregation. 256 thr = 4 waves, wave = 1 node.
// Lane covers 8 channels (bf16x8 16B gather = full 1KB row per wave instr).
// MODE 0: concat + bias + ReLU -> bf16 [N,512]
// MODE 1: head-mean + bias     -> fp32 [N,128]
// ---------------------------------------------------------------------------
template <int MODE>
__global__ __launch_bounds__(256) void gat_aggregate(const short* __restrict__ h,
                                                     const float* __restrict__ es,
                                                     const float* __restrict__ ed,
                                                     const int* __restrict__ offsets,
                                                     const int* __restrict__ adj,
                                                     const float* __restrict__ bias,
                                                     float* __restrict__ outf,
                                                     short* __restrict__ outb) {
    constexpr int CAP = 256;
    __shared__ int s_src[4][CAP];
    __shared__ float s_wt[4][4][CAP];  // [wave][head][edge]
    int tid = threadIdx.x, w = tid >> 6, lane = tid & 63;
    int n = blockIdx.x * 4 + w;  // grid = NN/4 exactly
    int row0 = offsets[n];
    int deg = offsets[n + 1] - row0;
    int tot = min(deg + 1, CAP);  // + self loop (deg << CAP always)
    for (int i = lane; i < tot; i += 64)
        s_src[w][i] = (i < deg) ? adj[row0 + i] : n;
    float4 edv = *(const float4*)&ed[n * 4];
    float mx0 = -1e30f, mx1 = -1e30f, mx2 = -1e30f, mx3 = -1e30f;
    for (int i = lane; i < tot; i += 64) {
        int s = s_src[w][i];  // written by this same lane
        float4 e4 = *(const float4*)&es[s * 4];
        float e0 = e4.x + edv.x; e0 = (e0 >= 0.f) ? e0 : 0.2f * e0;
        float e1 = e4.y + edv.y; e1 = (e1 >= 0.f) ? e1 : 0.2f * e1;
        float e2 = e4.z + edv.z; e2 = (e2 >= 0.f) ? e2 : 0.2f * e2;
        float e3 = e4.w + edv.w; e3 = (e3 >= 0.f) ? e3 : 0.2f * e3;
        s_wt[w][0][i] = e0; s_wt[w][1][i] = e1; s_wt[w][2][i] = e2; s_wt[w][3][i] = e3;
        mx0 = fmaxf(mx0, e0); mx1 = fmaxf(mx1, e1);
        mx2 = fmaxf(mx2, e2); mx3 = fmaxf(mx3, e3);
    }
#pragma unroll
    for (int o = 1; o < 64; o <<= 1) {
        mx0 = fmaxf(mx0, __shfl_xor(mx0, o));
        mx1 = fmaxf(mx1, __shfl_xor(mx1, o));
        mx2 = fmaxf(mx2, __shfl_xor(mx2, o));
        mx3 = fmaxf(mx3, __shfl_xor(mx3, o));
    }
    float s0 = 0.f, s1 = 0.f, s2 = 0.f, s3 = 0.f;
    for (int i = lane; i < tot; i += 64) {
        float v0 = __expf(s_wt[w][0][i] - mx0); s_wt[w][0][i] = v0; s0 += v0;
        float v1 = __expf(s_wt[w][1][i] - mx1); s_wt[w][1][i] = v1; s1 += v1;
        float v2 = __expf(s_wt[w][2][i] - mx2); s_wt[w][2][i] = v2; s2 += v2;
        float v3 = __expf(s_wt[w][3][i] - mx3); s_wt[w][3][i] = v3; s3 += v3;
    }
#pragma unroll
    for (int o = 1; o < 64; o <<= 1) {
        s0 += __shfl_xor(s0, o); s1 += __shfl_xor(s1, o);
        s2 += __shfl_xor(s2, o); s3 += __shfl_xor(s3, o);
    }
    __syncthreads();  // cross-lane s_src / s_wt visibility for gather
    int head = lane >> 4;
    float rd = 1.f / ((head == 0) ? s0 : (head == 1) ? s1 : (head == 2) ? s2 : s3);
    float acc[8] = {};
    const short* hbase = h + lane * 8;
    for (int i = 0; i < tot; i++) {
        int s = s_src[w][i];
        float wt = s_wt[w][head][i];
        bf16x8 hv = *(const bf16x8*)&hbase[(size_t)s * HF];
#pragma unroll
        for (int k = 0; k < 8; k++) acc[k] += wt * bf2f(hv[k]);
    }
#pragma unroll
    for (int k = 0; k < 8; k++) acc[k] *= rd;
    if (MODE == 0) {
        int c = lane * 8;
        float4 b0 = *(const float4*)&bias[c];
        float4 b1 = *(const float4*)&bias[c + 4];
        bf16x8 o;
        o[0] = f2bf(fmaxf(acc[0] + b0.x, 0.f));
        o[1] = f2bf(fmaxf(acc[1] + b0.y, 0.f));
        o[2] = f2bf(fmaxf(acc[2] + b0.z, 0.f));
        o[3] = f2bf(fmaxf(acc[3] + b0.w, 0.f));
        o[4] = f2bf(fmaxf(acc[4] + b1.x, 0.f));
        o[5] = f2bf(fmaxf(acc[5] + b1.y, 0.f));
        o[6] = f2bf(fmaxf(acc[6] + b1.z, 0.f));
        o[7] = f2bf(fmaxf(acc[7] + b1.w, 0.f));
        *(bf16x8*)&outb[(size_t)n * HF + c] = o;
    } else {
        // mean over heads: sum lanes lane^16, lane^32 (same channel slot)
#pragma unroll
        for (int k = 0; k < 8; k++) {
            acc[k] += __shfl_xor(acc[k], 16);
            acc[k] += __shfl_xor(acc[k], 32);
        }
        if (lane < 16) {
            int c = lane * 8;
#pragma unroll
            for (int k = 0; k < 8; k++)
                outf[(size_t)n * FF + c + k] = 0.25f * acc[k] + bias[c + k];
        }
    }
}

// ---------------------------------------------------------------------------
// Global mean pool (sum + count), low-contention: block handles 64 sorted nodes.
// ---------------------------------------------------------------------------
__global__ __launch_bounds__(128) void pool_kernel(const float* __restrict__ h2,
                                                   const int* __restrict__ batch,
                                                   float* __restrict__ sums,
                                                   float* __restrict__ cnts) {
    int f = threadIdx.x;  // 128 threads = feature
    int start = blockIdx.x * 64;
    float acc = 0.f;
    int curg = -1;
    for (int i = 0; i < 64; i++) {
        int node = start + i;
        if (node >= NN) break;
        int g = batch[node];
        if (g != curg) {
            if (curg >= 0) atomicAdd(&sums[curg * FF + f], acc);
            acc = 0.f;
            curg = g;
        }
        acc += h2[(size_t)node * FF + f];
    }
    if (curg >= 0) atomicAdd(&sums[curg * FF + f], acc);
    if (f == 0) {
        int cacc = 0, cg = -1;
        for (int i = 0; i < 64; i++) {
            int node = start + i;
            if (node >= NN) break;
            int g = batch[node];
            if (g != cg) {
                if (cg >= 0) atomicAdd(&cnts[cg], (float)cacc);
                cacc = 0;
                cg = g;
            }
            cacc++;
        }
        if (cg >= 0) atomicAdd(&cnts[cg], (float)cacc);
    }
}

// ---------------------------------------------------------------------------
// Final MLP: g = sums/cnt; z = relu(g@Wr1+br1); out = z@Wr2+br2.  Block/graph.
// ---------------------------------------------------------------------------
__global__ __launch_bounds__(256) void mlp_kernel(const float* __restrict__ sums,
                                                  const float* __restrict__ cnts,
                                                  const float* __restrict__ Wr1,
                                                  const float* __restrict__ br1,
                                                  const float* __restrict__ Wr2,
                                                  const float* __restrict__ br2,
                                                  float* __restrict__ out) {
    int g = blockIdx.x, t = threadIdx.x;
    __shared__ float gv[128];
    __shared__ float z[128];
    float c = fmaxf(cnts[g], 1.0f);
    if (t < 128) gv[t] = sums[g * FF + t] / c;
    __syncthreads();
    if (t < 128) {
        float a = br1[t];
        for (int k = 0; k < 128; k++) a += gv[k] * Wr1[k * 128 + t];
        z[t] = fmaxf(a, 0.f);
    }
    __syncthreads();
    {
        float a = br2[t];
        for (int k = 0; k < 128; k++) a += z[k] * Wr2[k * 256 + t];
        out[g * 256 + t] = a;
    }
}

// ---------------------------------------------------------------------------
extern "C" void kernel_launch(void* const* d_in, const int* in_sizes, int n_in,
                              void* d_out, int out_size, void* d_ws, size_t ws_size,
                              hipStream_t stream) {
    const float* x    = (const float*)d_in[0];
    const int*   ei   = (const int*)d_in[1];
    const int*   batch= (const int*)d_in[2];
    const float* W0   = (const float*)d_in[3];
    const float* as0  = (const float*)d_in[4];
    const float* ad0  = (const float*)d_in[5];
    const float* b0   = (const float*)d_in[6];
    const float* W1   = (const float*)d_in[7];
    const float* as1  = (const float*)d_in[8];
    const float* ad1  = (const float*)d_in[9];
    const float* b1   = (const float*)d_in[10];
    const float* W2   = (const float*)d_in[11];
    const float* as2  = (const float*)d_in[12];
    const float* ad2  = (const float*)d_in[13];
    const float* b2   = (const float*)d_in[14];
    const float* Wr1  = (const float*)d_in[15];
    const float* br1  = (const float*)d_in[16];
    const float* Wr2  = (const float*)d_in[17];
    const float* br2  = (const float*)d_in[18];
    float* out = (float*)d_out;

    char* p = (char*)d_ws;
    auto alloc = [&](size_t bytes) {
        char* r = p;
        p += (bytes + 255) / 256 * 256;
        return r;
    };
    short* hA      = (short*)alloc((size_t)NN * HF * 2);   // GEMM out (bf16)
    short* hB      = (short*)alloc((size_t)NN * HF * 2);   // aggregate out (bf16)
    float* h2      = (float*)alloc((size_t)NN * FF * 4);
    short* xb      = (short*)alloc((size_t)NN * 64 * 2);
    short* T0h     = (short*)alloc((size_t)HF * 64 * 2);
    short* T0l     = (short*)alloc((size_t)HF * 64 * 2);
    short* T1h     = (short*)alloc((size_t)HF * HF * 2);
    short* T1l     = (short*)alloc((size_t)HF * HF * 2);
    short* T2h     = (short*)alloc((size_t)HF * HF * 2);
    short* T2l     = (short*)alloc((size_t)HF * HF * 2);
    float* es      = (float*)alloc((size_t)NN * HH * 4);
    float* ed      = (float*)alloc((size_t)NN * HH * 4);
    int*   counts  = (int*)alloc((size_t)NN * 4);
    int*   offsets = (int*)alloc((size_t)(NN + 1) * 4);
    int*   cursor  = (int*)alloc((size_t)NN * 4);
    int*   adj     = (int*)alloc((size_t)NE * 4);
    float* sums    = (float*)alloc((size_t)GG * FF * 4);
    float* cnts    = (float*)alloc((size_t)GG * 4);

    // ---- CSR build (reused by all 3 layers) ----
    hipMemsetAsync(counts, 0, NN * 4, stream);
    count_edges<<<(NE + 255) / 256, 256, 0, stream>>>(ei, counts);
    scan_offsets<<<1, 1024, 0, stream>>>(counts, offsets, cursor);
    scatter_edges<<<(NE + 255) / 256, 256, 0, stream>>>(ei, cursor, adj);

    // ---- prep: weight transposes (hi/lo) + x conversion, one launch ----
    prep_kernel<<<dim3(16, 16, 4), 256, 0, stream>>>(x, xb, W0, W1, W2,
                                                     T0h, T0l, T1h, T1l, T2h, T2l);

    dim3 ggemm((NN + 127) / 128, HH);

    // ---- layer 0 (K=64) ----
    gemm_attn<<<ggemm, 256, 0, stream>>>(xb, T0h, T0l, hA, es, ed, as0, ad0, NN, 64);
    gat_aggregate<0><<<NN / 4, 256, 0, stream>>>(hA, es, ed, offsets, adj, b0, nullptr, hB);

    // ---- layer 1 (K=512) ----
    gemm_attn<<<ggemm, 256, 0, stream>>>(hB, T1h, T1l, hA, es, ed, as1, ad1, NN, HF);
    gat_aggregate<0><<<NN / 4, 256, 0, stream>>>(hA, es, ed, offsets, adj, b1, nullptr, hB);

    // ---- layer 2 (K=512) ----
    gemm_attn<<<ggemm, 256, 0, stream>>>(hB, T2h, T2l, hA, es, ed, as2, ad2, NN, HF);
    gat_aggregate<1><<<NN / 4, 256, 0, stream>>>(hA, es, ed, offsets, adj, b2, h2, nullptr);

    // ---- pool + MLP ----
    hipMemsetAsync(sums, 0, (GG * FF + GG) * 4, stream);  // sums and cnts contiguous
    pool_kernel<<<(NN + 63) / 64, 128, 0, stream>>>(h2, batch, sums, cnts);
    mlp_kernel<<<GG, 256, 0, stream>>>(sums, cnts, Wr1, br1, Wr2, br2, out);
}

// Round 4
// 220.311 us; speedup vs baseline: 2.3985x; 1.0065x over previous
//
#include <hip/hip_runtime.h>
#include <hip/hip_bf16.h>
#include <math.h>

// Problem constants (from reference)
constexpr int NN  = 10000;   // nodes
constexpr int NE  = 160000;  // edges (before self loops)
constexpr int GG  = 16;      // graphs
constexpr int HH  = 4;       // heads
constexpr int FF  = 128;     // per-head channels
constexpr int HF  = 512;     // H*F

typedef __attribute__((ext_vector_type(8))) short bf16x8;
typedef __attribute__((ext_vector_type(4))) float f32x4;

__device__ inline short f2bf(float v) {
    __hip_bfloat16 h = __float2bfloat16(v);
    return *reinterpret_cast<short*>(&h);
}
__device__ inline float bf2f(short s) {
    __hip_bfloat16 h = *reinterpret_cast<__hip_bfloat16*>(&s);
    return __bfloat162float(h);
}

// ---------------------------------------------------------------------------
// Zero scratch (replaces hipMemsetAsync fills): counts[NN], sums[GG*FF+GG]
// ---------------------------------------------------------------------------
__global__ __launch_bounds__(256) void zero_kernel(int* __restrict__ counts,
                                                   float* __restrict__ sums) {
    int i = blockIdx.x * 256 + threadIdx.x;
    if (i < NN) counts[i] = 0;
    if (i < GG * FF + GG) sums[i] = 0.f;
}

// ---------------------------------------------------------------------------
// CSR build: group edges by dst. Self loops handled implicitly in aggregate.
// ---------------------------------------------------------------------------
__global__ void count_edges(const int* __restrict__ ei, int* __restrict__ counts) {
    int e = blockIdx.x * 256 + threadIdx.x;
    if (e < NE) atomicAdd(&counts[ei[NE + e]], 1);
}

__global__ __launch_bounds__(1024) void scan_offsets(const int* __restrict__ counts,
                                                     int* __restrict__ offsets,
                                                     int* __restrict__ cursor) {
    __shared__ int wsum[16];
    __shared__ int carry;
    int tid = threadIdx.x, lane = tid & 63, wv = tid >> 6;
    if (tid == 0) carry = 0;
    __syncthreads();
    for (int base = 0; base < NN; base += 1024) {
        int i = base + tid;
        int v = (i < NN) ? counts[i] : 0;
        int x = v;
#pragma unroll
        for (int st = 1; st < 64; st <<= 1) {
            int t = __shfl_up(x, st);
            if (lane >= st) x += t;
        }
        if (lane == 63) wsum[wv] = x;
        __syncthreads();
        if (tid == 0) {
            int s = carry;
            for (int k2 = 0; k2 < 16; k2++) { int t = wsum[k2]; wsum[k2] = s; s += t; }
            carry = s;
        }
        __syncthreads();
        int excl = wsum[wv] + x - v;
        if (i < NN) { offsets[i] = excl; cursor[i] = excl; }
        __syncthreads();
    }
    if (tid == 0) offsets[NN] = carry;
}

__global__ void scatter_edges(const int* __restrict__ ei, int* __restrict__ cursor,
                              int* __restrict__ adj) {
    int e = blockIdx.x * 256 + threadIdx.x;
    if (e < NE) {
        int dst = ei[NE + e];
        int pos = atomicAdd(&cursor[dst], 1);
        adj[pos] = ei[e];  // store src
    }
}

// ---------------------------------------------------------------------------
// Prep: z=0..2 -> W{z} [K,512] fp32 -> W^T hi/lo bf16 [512,K]; z=3 -> x->bf16
// ---------------------------------------------------------------------------
__global__ __launch_bounds__(256) void prep_kernel(const float* __restrict__ x,
                                                   short* __restrict__ xb,
                                                   const float* __restrict__ W0,
                                                   const float* __restrict__ W1,
                                                   const float* __restrict__ W2,
                                                   short* __restrict__ T0h, short* __restrict__ T0l,
                                                   short* __restrict__ T1h, short* __restrict__ T1l,
                                                   short* __restrict__ T2h, short* __restrict__ T2l) {
    int z = blockIdx.z;
    int tid = threadIdx.x;
    if (z == 3) {
        int bid = blockIdx.y * 16 + blockIdx.x;
        for (int i = bid * 256 + tid; i < NN * 64; i += 256 * 256)
            xb[i] = f2bf(x[i]);
        return;
    }
    const float* W = (z == 0) ? W0 : (z == 1) ? W1 : W2;
    short* Th = (z == 0) ? T0h : (z == 1) ? T1h : T2h;
    short* Tl = (z == 0) ? T0l : (z == 1) ? T1l : T2l;
    int K = (z == 0) ? 64 : HF;
    int bn = blockIdx.x * 32, bk = blockIdx.y * 32;
    if (bk >= K) return;  // block-uniform
    __shared__ float tile[32][33];
    int tx = tid & 31, ty = tid >> 5;  // ty 0..7
    for (int r = ty; r < 32; r += 8) {
        int k = bk + r, n = bn + tx;
        tile[r][tx] = W[(size_t)k * HF + n];
    }
    __syncthreads();
    for (int r = ty; r < 32; r += 8) {
        int n = bn + r, k = bk + tx;
        float v = tile[tx][r];
        short hi = f2bf(v);
        short lo = f2bf(v - bf2f(hi));
        Th[(size_t)n * K + k] = hi;
        Tl[(size_t)n * K + k] = lo;
    }
}

// ---------------------------------------------------------------------------
// bf16 MFMA GEMM + fused attention coefficients.
// C[M,512]bf16 = A[M,K]bf16 @ (Bhi+Blo)[512,K]^T, fp32 accum.
// BM=64, BN=128 = one head (blockIdx.y), BK=32, 4 waves; wave = 64 rows x 32
// cols (af[4] x b[2] frags -> 16 MFMA : 8 ds_read_b128 per K-step).
// Grid 157x4 = 628 blocks (vs 316 before): fixes CU starvation/imbalance.
// Epilogue: es[row,head] = C_row . a_s[head], ed likewise (fp32, exact),
// then C stored as bf16.
// ---------------------------------------------------------------------------
__global__ __launch_bounds__(256) void gemm_attn(const short* __restrict__ A,
                                                 const short* __restrict__ Bhi,
                                                 const short* __restrict__ Blo,
                                                 short* __restrict__ Cb,
                                                 float* __restrict__ es,
                                                 float* __restrict__ ed,
                                                 const float* __restrict__ a_s,
                                                 const float* __restrict__ a_d,
                                                 int M, int K) {
    constexpr int BM = 64, BK = 32, LDT = BK + 8;  // pad 16B
    __shared__ short As[BM][LDT];
    __shared__ short Bh[FF][LDT];
    __shared__ short Bl[FF][LDT];
    __shared__ float s_red[4][BM][2];
    int tid = threadIdx.x;
    int wave = tid >> 6, lane = tid & 63;
    int fr = lane & 15, fq = lane >> 4;
    int bm = blockIdx.x * BM;
    int head = blockIdx.y;
    int bn = head * FF;
    int arow = tid >> 2, acol = (tid & 3) * 8;   // A: 64x32, 8 shorts/thread
    int brow = tid >> 1, bcol = (tid & 1) * 16;  // B: 128x32, 16 shorts/thread
    f32x4 acc[4][2] = {};
    for (int k0 = 0; k0 < K; k0 += BK) {
        {
            int row = bm + arow;
            bf16x8 va = {};
            if (row < M) va = *(const bf16x8*)&A[(size_t)row * K + k0 + acol];
            *(bf16x8*)&As[arow][acol] = va;
            const short* bsh = &Bhi[(size_t)(bn + brow) * K + k0 + bcol];
            *(bf16x8*)&Bh[brow][bcol]     = *(const bf16x8*)bsh;
            *(bf16x8*)&Bh[brow][bcol + 8] = *(const bf16x8*)(bsh + 8);
            const short* bsl = &Blo[(size_t)(bn + brow) * K + k0 + bcol];
            *(bf16x8*)&Bl[brow][bcol]     = *(const bf16x8*)bsl;
            *(bf16x8*)&Bl[brow][bcol + 8] = *(const bf16x8*)(bsl + 8);
        }
        __syncthreads();
        bf16x8 af[4], bh[2], bl[2];
#pragma unroll
        for (int m = 0; m < 4; m++)
            af[m] = *(const bf16x8*)&As[m * 16 + fr][fq * 8];
#pragma unroll
        for (int n = 0; n < 2; n++) {
            bh[n] = *(const bf16x8*)&Bh[wave * 32 + n * 16 + fr][fq * 8];
            bl[n] = *(const bf16x8*)&Bl[wave * 32 + n * 16 + fr][fq * 8];
        }
#pragma unroll
        for (int m = 0; m < 4; m++)
#pragma unroll
            for (int n = 0; n < 2; n++) {
                acc[m][n] = __builtin_amdgcn_mfma_f32_16x16x32_bf16(af[m], bh[n], acc[m][n], 0, 0, 0);
                acc[m][n] = __builtin_amdgcn_mfma_f32_16x16x32_bf16(af[m], bl[n], acc[m][n], 0, 0, 0);
            }
        __syncthreads();
    }
    // ---- epilogue: fused attn dots + bf16 C store ----
    // C/D layout: col = lane&15, row = (lane>>4)*4 + j   [verified m89]
    float asv[2], adv[2];
#pragma unroll
    for (int n = 0; n < 2; n++) {
        int c = wave * 32 + n * 16 + fr;
        asv[n] = a_s[head * FF + c];
        adv[n] = a_d[head * FF + c];
    }
#pragma unroll
    for (int m = 0; m < 4; m++) {
#pragma unroll
        for (int j = 0; j < 4; j++) {
            float ps = 0.f, pd = 0.f;
#pragma unroll
            for (int n = 0; n < 2; n++) {
                float v = acc[m][n][j];
                ps += v * asv[n];
                pd += v * adv[n];
            }
#pragma unroll
            for (int o = 1; o < 16; o <<= 1) {
                ps += __shfl_xor(ps, o);
                pd += __shfl_xor(pd, o);
            }
            int rloc = m * 16 + fq * 4 + j;
            if (fr == 0) { s_red[wave][rloc][0] = ps; s_red[wave][rloc][1] = pd; }
            int row = bm + rloc;
            if (row < M) {
#pragma unroll
                for (int n = 0; n < 2; n++)
                    Cb[(size_t)row * HF + bn + wave * 32 + n * 16 + fr] = f2bf(acc[m][n][j]);
            }
        }
    }
    __syncthreads();
    if (tid < BM) {
        int row = bm + tid;
        if (row < M) {
            es[row * 4 + head] = s_red[0][tid][0] + s_red[1][tid][0] +
                                 s_red[2][tid][0] + s_red[3][tid][0];
            ed[row * 4 + head] = s_red[0][tid][1] + s_red[1][tid][1] +
                                 s_red[2][tid][1] + s_red[3][tid][1];
        }
    }
}

// ---------------------------------------------------------------------------
// Segment softmax + aggregation. 256 thr = 4 waves, wave = 1 node.
// Lane covers 8 channels (bf16x8 16B gather = full 1KB row per wave instr).
// MODE 0: concat + bias + ReLU -> bf16 [N,512]
// MODE 1: head-mean + bias     -> fp32 [N,128]
// ---------------------------------------------------------------------------
template <int MODE>
__global__ __launch_bounds__(256) void gat_aggregate(const short* __restrict__ h,
                                                     const float* __restrict__ es,
                                                     const float* __restrict__ ed,
                                                     const int* __restrict__ offsets,
                                                     const int* __restrict__ adj,
                                                     const float* __restrict__ bias,
                                                     float* __restrict__ outf,
                                                     short* __restrict__ outb) {
    constexpr int CAP = 256;
    __shared__ int s_src[4][CAP];
    __shared__ float s_wt[4][4][CAP];  // [wave][head][edge]
    int tid = threadIdx.x, w = tid >> 6, lane = tid & 63;
    int n = blockIdx.x * 4 + w;  // grid = NN/4 exactly
    int row0 = offsets[n];
    int deg = offsets[n + 1] - row0;
    int tot = min(deg + 1, CAP);  // + self loop (deg << CAP always)
    for (int i = lane; i < tot; i += 64)
        s_src[w][i] = (i < deg) ? adj[row0 + i] : n;
    float4 edv = *(const float4*)&ed[n * 4];
    float mx0 = -1e30f, mx1 = -1e30f, mx2 = -1e30f, mx3 = -1e30f;
    for (int i = lane; i < tot; i += 64) {
        int s = s_src[w][i];  // written by this same lane
        float4 e4 = *(const float4*)&es[s * 4];
        float e0 = e4.x + edv.x; e0 = (e0 >= 0.f) ? e0 : 0.2f * e0;
        float e1 = e4.y + edv.y; e1 = (e1 >= 0.f) ? e1 : 0.2f * e1;
        float e2 = e4.z + edv.z; e2 = (e2 >= 0.f) ? e2 : 0.2f * e2;
        float e3 = e4.w + edv.w; e3 = (e3 >= 0.f) ? e3 : 0.2f * e3;
        s_wt[w][0][i] = e0; s_wt[w][1][i] = e1; s_wt[w][2][i] = e2; s_wt[w][3][i] = e3;
        mx0 = fmaxf(mx0, e0); mx1 = fmaxf(mx1, e1);
        mx2 = fmaxf(mx2, e2); mx3 = fmaxf(mx3, e3);
    }
#pragma unroll
    for (int o = 1; o < 64; o <<= 1) {
        mx0 = fmaxf(mx0, __shfl_xor(mx0, o));
        mx1 = fmaxf(mx1, __shfl_xor(mx1, o));
        mx2 = fmaxf(mx2, __shfl_xor(mx2, o));
        mx3 = fmaxf(mx3, __shfl_xor(mx3, o));
    }
    float s0 = 0.f, s1 = 0.f, s2 = 0.f, s3 = 0.f;
    for (int i = lane; i < tot; i += 64) {
        float v0 = __expf(s_wt[w][0][i] - mx0); s_wt[w][0][i] = v0; s0 += v0;
        float v1 = __expf(s_wt[w][1][i] - mx1); s_wt[w][1][i] = v1; s1 += v1;
        float v2 = __expf(s_wt[w][2][i] - mx2); s_wt[w][2][i] = v2; s2 += v2;
        float v3 = __expf(s_wt[w][3][i] - mx3); s_wt[w][3][i] = v3; s3 += v3;
    }
#pragma unroll
    for (int o = 1; o < 64; o <<= 1) {
        s0 += __shfl_xor(s0, o); s1 += __shfl_xor(s1, o);
        s2 += __shfl_xor(s2, o); s3 += __shfl_xor(s3, o);
    }
    __syncthreads();  // cross-lane s_src / s_wt visibility for gather
    int head = lane >> 4;
    float rd = 1.f / ((head == 0) ? s0 : (head == 1) ? s1 : (head == 2) ? s2 : s3);
    float acc[8] = {};
    const short* hbase = h + lane * 8;
    for (int i = 0; i < tot; i++) {
        int s = s_src[w][i];
        float wt = s_wt[w][head][i];
        bf16x8 hv = *(const bf16x8*)&hbase[(size_t)s * HF];
#pragma unroll
        for (int k = 0; k < 8; k++) acc[k] += wt * bf2f(hv[k]);
    }
#pragma unroll
    for (int k = 0; k < 8; k++) acc[k] *= rd;
    if (MODE == 0) {
        int c = lane * 8;
        float4 b0 = *(const float4*)&bias[c];
        float4 b1 = *(const float4*)&bias[c + 4];
        bf16x8 o;
        o[0] = f2bf(fmaxf(acc[0] + b0.x, 0.f));
        o[1] = f2bf(fmaxf(acc[1] + b0.y, 0.f));
        o[2] = f2bf(fmaxf(acc[2] + b0.z, 0.f));
        o[3] = f2bf(fmaxf(acc[3] + b0.w, 0.f));
        o[4] = f2bf(fmaxf(acc[4] + b1.x, 0.f));
        o[5] = f2bf(fmaxf(acc[5] + b1.y, 0.f));
        o[6] = f2bf(fmaxf(acc[6] + b1.z, 0.f));
        o[7] = f2bf(fmaxf(acc[7] + b1.w, 0.f));
        *(bf16x8*)&outb[(size_t)n * HF + c] = o;
    } else {
        // mean over heads: sum lanes lane^16, lane^32 (same channel slot)
#pragma unroll
        for (int k = 0; k < 8; k++) {
            acc[k] += __shfl_xor(acc[k], 16);
            acc[k] += __shfl_xor(acc[k], 32);
        }
        if (lane < 16) {
            int c = lane * 8;
#pragma unroll
            for (int k = 0; k < 8; k++)
                outf[(size_t)n * FF + c + k] = 0.25f * acc[k] + bias[c + k];
        }
    }
}

// ---------------------------------------------------------------------------
// Global mean pool (sum + count), low-contention: block handles 64 sorted nodes.
// ---------------------------------------------------------------------------
__global__ __launch_bounds__(128) void pool_kernel(const float* __restrict__ h2,
                                                   const int* __restrict__ batch,
                                                   float* __restrict__ sums,
                                                   float* __restrict__ cnts) {
    int f = threadIdx.x;  // 128 threads = feature
    int start = blockIdx.x * 64;
    float acc = 0.f;
    int curg = -1;
    for (int i = 0; i < 64; i++) {
        int node = start + i;
        if (node >= NN) break;
        int g = batch[node];
        if (g != curg) {
            if (curg >= 0) atomicAdd(&sums[curg * FF + f], acc);
            acc = 0.f;
            curg = g;
        }
        acc += h2[(size_t)node * FF + f];
    }
    if (curg >= 0) atomicAdd(&sums[curg * FF + f], acc);
    if (f == 0) {
        int cacc = 0, cg = -1;
        for (int i = 0; i < 64; i++) {
            int node = start + i;
            if (node >= NN) break;
            int g = batch[node];
            if (g != cg) {
                if (cg >= 0) atomicAdd(&cnts[cg], (float)cacc);
                cacc = 0;
                cg = g;
            }
            cacc++;
        }
        if (cg >= 0) atomicAdd(&cnts[cg], (float)cacc);
    }
}

// ---------------------------------------------------------------------------
// Final MLP: g = sums/cnt; z = relu(g@Wr1+br1); out = z@Wr2+br2.  Block/graph.
// ---------------------------------------------------------------------------
__global__ __launch_bounds__(256) void mlp_kernel(const float* __restrict__ sums,
                                                  const float* __restrict__ cnts,
                                                  const float* __restrict__ Wr1,
                                                  const float* __restrict__ br1,
                                                  const float* __restrict__ Wr2,
                                                  const float* __restrict__ br2,
                                                  float* __restrict__ out) {
    int g = blockIdx.x, t = threadIdx.x;
    __shared__ float gv[128];
    __shared__ float z[128];
    float c = fmaxf(cnts[g], 1.0f);
    if (t < 128) gv[t] = sums[g * FF + t] / c;
    __syncthreads();
    if (t < 128) {
        float a = br1[t];
        for (int k = 0; k < 128; k++) a += gv[k] * Wr1[k * 128 + t];
        z[t] = fmaxf(a, 0.f);
    }
    __syncthreads();
    {
        float a = br2[t];
        for (int k = 0; k < 128; k++) a += z[k] * Wr2[k * 256 + t];
        out[g * 256 + t] = a;
    }
}

// ---------------------------------------------------------------------------
extern "C" void kernel_launch(void* const* d_in, const int* in_sizes, int n_in,
                              void* d_out, int out_size, void* d_ws, size_t ws_size,
                              hipStream_t stream) {
    const float* x    = (const float*)d_in[0];
    const int*   ei   = (const int*)d_in[1];
    const int*   batch= (const int*)d_in[2];
    const float* W0   = (const float*)d_in[3];
    const float* as0  = (const float*)d_in[4];
    const float* ad0  = (const float*)d_in[5];
    const float* b0   = (const float*)d_in[6];
    const float* W1   = (const float*)d_in[7];
    const float* as1  = (const float*)d_in[8];
    const float* ad1  = (const float*)d_in[9];
    const float* b1   = (const float*)d_in[10];
    const float* W2   = (const float*)d_in[11];
    const float* as2  = (const float*)d_in[12];
    const float* ad2  = (const float*)d_in[13];
    const float* b2   = (const float*)d_in[14];
    const float* Wr1  = (const float*)d_in[15];
    const float* br1  = (const float*)d_in[16];
    const float* Wr2  = (const float*)d_in[17];
    const float* br2  = (const float*)d_in[18];
    float* out = (float*)d_out;

    char* p = (char*)d_ws;
    auto alloc = [&](size_t bytes) {
        char* r = p;
        p += (bytes + 255) / 256 * 256;
        return r;
    };
    short* hA      = (short*)alloc((size_t)NN * HF * 2);   // GEMM out (bf16)
    short* hB      = (short*)alloc((size_t)NN * HF * 2);   // aggregate out (bf16)
    float* h2      = (float*)alloc((size_t)NN * FF * 4);
    short* xb      = (short*)alloc((size_t)NN * 64 * 2);
    short* T0h     = (short*)alloc((size_t)HF * 64 * 2);
    short* T0l     = (short*)alloc((size_t)HF * 64 * 2);
    short* T1h     = (short*)alloc((size_t)HF * HF * 2);
    short* T1l     = (short*)alloc((size_t)HF * HF * 2);
    short* T2h     = (short*)alloc((size_t)HF * HF * 2);
    short* T2l     = (short*)alloc((size_t)HF * HF * 2);
    float* es      = (float*)alloc((size_t)NN * HH * 4);
    float* ed      = (float*)alloc((size_t)NN * HH * 4);
    int*   counts  = (int*)alloc((size_t)NN * 4);
    int*   offsets = (int*)alloc((size_t)(NN + 1) * 4);
    int*   cursor  = (int*)alloc((size_t)NN * 4);
    int*   adj     = (int*)alloc((size_t)NE * 4);
    float* sums    = (float*)alloc((size_t)GG * FF * 4);
    float* cnts    = (float*)alloc((size_t)GG * 4);

    // ---- zero scratch (counts for CSR atomics, sums/cnts for pool) ----
    zero_kernel<<<(NN + 255) / 256, 256, 0, stream>>>(counts, sums);

    // ---- CSR build (reused by all 3 layers) ----
    count_edges<<<(NE + 255) / 256, 256, 0, stream>>>(ei, counts);
    scan_offsets<<<1, 1024, 0, stream>>>(counts, offsets, cursor);
    scatter_edges<<<(NE + 255) / 256, 256, 0, stream>>>(ei, cursor, adj);

    // ---- prep: weight transposes (hi/lo) + x conversion, one launch ----
    prep_kernel<<<dim3(16, 16, 4), 256, 0, stream>>>(x, xb, W0, W1, W2,
                                                     T0h, T0l, T1h, T1l, T2h, T2l);

    dim3 ggemm((NN + 63) / 64, HH);

    // ---- layer 0 (K=64) ----
    gemm_attn<<<ggemm, 256, 0, stream>>>(xb, T0h, T0l, hA, es, ed, as0, ad0, NN, 64);
    gat_aggregate<0><<<NN / 4, 256, 0, stream>>>(hA, es, ed, offsets, adj, b0, nullptr, hB);

    // ---- layer 1 (K=512) ----
    gemm_attn<<<ggemm, 256, 0, stream>>>(hB, T1h, T1l, hA, es, ed, as1, ad1, NN, HF);
    gat_aggregate<0><<<NN / 4, 256, 0, stream>>>(hA, es, ed, offsets, adj, b1, nullptr, hB);

    // ---- layer 2 (K=512) ----
    gemm_attn<<<ggemm, 256, 0, stream>>>(hB, T2h, T2l, hA, es, ed, as2, ad2, NN, HF);
    gat_aggregate<1><<<NN / 4, 256, 0, stream>>>(hA, es, ed, offsets, adj, b2, h2, nullptr);

    // ---- pool + MLP ----
    pool_kernel<<<(NN + 63) / 64, 128, 0, stream>>>(h2, batch, sums, cnts);
    mlp_kernel<<<GG, 256, 0, stream>>>(sums, cnts, Wr1, br1, Wr2, br2, out);
}